// Round 2
// baseline (8938.018 us; speedup 1.0000x reference)
//
#include <hip/hip_runtime.h>
#include <cstddef>
#include <cstdint>

#define B_  4096
#define T_  48
#define Z_  1000
#define L_  64
#define OH_ 128
#define EH_ 256

// NaN-safe fast tanh: 1 - 2/(exp(2x)+1).  exp(+inf)->inf -> 1, exp(-inf)->0 -> -1.
__device__ __forceinline__ float tanh_f(float x) {
    float t = __expf(2.0f * x);
    return 1.0f - __fdividef(2.0f, t + 1.0f);
}

// ---------------------------------------------------------------------------
// Kernel 1: encoder + z0 + precompute c = bi + [person,work,home] @ Wi[65:225]
// 512 blocks x 256 threads, 8 samples/block.
// ---------------------------------------------------------------------------
__global__ __launch_bounds__(256) void enc_kernel(
    const float* __restrict__ person, const int* __restrict__ homeid,
    const int* __restrict__ workid, const float* __restrict__ purpose,
    const float* __restrict__ eps, const float* __restrict__ ztab,
    const float* __restrict__ W1, const float* __restrict__ b1,
    const float* __restrict__ W2, const float* __restrict__ b2,
    const float* __restrict__ Wi, const float* __restrict__ bi,
    float* __restrict__ outMu, float* __restrict__ outLv,
    float* __restrict__ zs0, float* __restrict__ cbuf)
{
    __shared__ float inT[168][8];   // [k][s] transposed input (enc_in order)
    __shared__ float hT[256][8];
    __shared__ float latT[128][8];

    const int tid = threadIdx.x;
    const int sb  = blockIdx.x * 8;

    // gather enc_in = [person(0:32), home(32:96), work(96:160), purpose(160:168)]
    for (int idx = tid; idx < 168 * 8; idx += 256) {
        int k = idx >> 3, s = idx & 7, b = sb + s;
        float v;
        if (k < 32)       v = person[b * 32 + k];
        else if (k < 96)  v = ztab[homeid[b] * 64 + (k - 32)];
        else if (k < 160) v = ztab[workid[b] * 64 + (k - 96)];
        else              v = purpose[b * 8 + (k - 160)];
        inT[k][s] = v;
    }
    __syncthreads();

    // GEMM1: h = relu(enc_in @ W1 + b1); thread = output neuron j (256)
    {
        float bb = b1[tid];
        float a0 = bb, a1 = bb, a2 = bb, a3 = bb, a4 = bb, a5 = bb, a6 = bb, a7 = bb;
        #pragma unroll 4
        for (int k = 0; k < 168; ++k) {
            float w = W1[k * 256 + tid];
            float4 xlo = *(const float4*)&inT[k][0];
            float4 xhi = *(const float4*)&inT[k][4];
            a0 += w * xlo.x; a1 += w * xlo.y; a2 += w * xlo.z; a3 += w * xlo.w;
            a4 += w * xhi.x; a5 += w * xhi.y; a6 += w * xhi.z; a7 += w * xhi.w;
        }
        *(float4*)&hT[tid][0] = make_float4(fmaxf(a0, 0.f), fmaxf(a1, 0.f), fmaxf(a2, 0.f), fmaxf(a3, 0.f));
        *(float4*)&hT[tid][4] = make_float4(fmaxf(a4, 0.f), fmaxf(a5, 0.f), fmaxf(a6, 0.f), fmaxf(a7, 0.f));
    }
    __syncthreads();

    const int j  = tid & 127;       // output neuron
    const int sh = tid >> 7;        // sample half: 4 samples each

    // GEMM2: latent = h @ W2 + b2
    {
        float bb = b2[j];
        float a0 = bb, a1 = bb, a2 = bb, a3 = bb;
        #pragma unroll 4
        for (int k = 0; k < 256; ++k) {
            float w = W2[k * 128 + j];
            float4 x = *(const float4*)&hT[k][sh * 4];
            a0 += w * x.x; a1 += w * x.y; a2 += w * x.z; a3 += w * x.w;
        }
        *(float4*)&latT[j][sh * 4] = make_float4(a0, a1, a2, a3);
    }

    // c[s][j] = bi[j] + person@Wi[65:97] + work@Wi[97:161] + home@Wi[161:225]
    // (ODE input x = [z(0:64), t(64), person(65:97), work(97:161), home(161:225)])
    {
        float bb = bi[j];
        float a0 = bb, a1 = bb, a2 = bb, a3 = bb;
        #pragma unroll 4
        for (int k = 0; k < 32; ++k) {            // person: inT rows 0..31
            float w = Wi[(65 + k) * 128 + j];
            float4 x = *(const float4*)&inT[k][sh * 4];
            a0 += w * x.x; a1 += w * x.y; a2 += w * x.z; a3 += w * x.w;
        }
        #pragma unroll 4
        for (int k = 0; k < 64; ++k) {            // work: inT rows 96..159
            float w = Wi[(97 + k) * 128 + j];
            float4 x = *(const float4*)&inT[96 + k][sh * 4];
            a0 += w * x.x; a1 += w * x.y; a2 += w * x.z; a3 += w * x.w;
        }
        #pragma unroll 4
        for (int k = 0; k < 64; ++k) {            // home: inT rows 32..95
            float w = Wi[(161 + k) * 128 + j];
            float4 x = *(const float4*)&inT[32 + k][sh * 4];
            a0 += w * x.x; a1 += w * x.y; a2 += w * x.z; a3 += w * x.w;
        }
        cbuf[(size_t)(sb + sh * 4 + 0) * 128 + j] = a0;
        cbuf[(size_t)(sb + sh * 4 + 1) * 128 + j] = a1;
        cbuf[(size_t)(sb + sh * 4 + 2) * 128 + j] = a2;
        cbuf[(size_t)(sb + sh * 4 + 3) * 128 + j] = a3;
    }
    __syncthreads();

    // z0 = mu + eps * exp(0.5*log_var); also emit mu / log_var outputs
    {
        int jj = tid & 63, g = tid >> 6;  // g in 0..3 -> 2 samples each
        #pragma unroll
        for (int u = 0; u < 2; ++u) {
            int s = g * 2 + u, b = sb + s;
            float mu = latT[jj][s];
            float lv = latT[jj + 64][s];
            float z0 = mu + eps[(size_t)b * 64 + jj] * __expf(0.5f * lv);
            outMu[(size_t)b * 64 + jj] = mu;
            outLv[(size_t)b * 64 + jj] = lv;
            zs0[(size_t)b * 64 + jj]   = z0;
        }
    }
}

// ---------------------------------------------------------------------------
// Kernel 2: RK4 Neural-ODE integration.
// 256 blocks x 512 threads, 16 samples/block (1 block/CU, 8 waves/CU —
// same wave count as the 8-sample/256-thread/2-block config, but HALF the
// per-eval L2 weight traffic: ~321KB/eval/block amortized over 2x samples).
// Activations in LDS transposed [dim][sample] (pad 18 keeps float2 align for
// odd k and spreads banks); activation reads are wave-uniform broadcasts;
// weight loads are coalesced 512B/wave float2 streams (L2-resident).
// Thread mapping (matmul stages): j2 = (tid&63)*2 (2 neurons), s2 = (tid>>6)*2
// (2 of 16 samples).
// ---------------------------------------------------------------------------
__global__ __launch_bounds__(512, 1) void ode_kernel(
    float* __restrict__ zs,          // [T][B][L]; zs[0] pre-filled with z0
    const float* __restrict__ cbuf,  // [B][OH]
    const float* __restrict__ times, // [T]
    const float* __restrict__ Wi,    // [225][128]
    const float* __restrict__ r1W1, const float* __restrict__ r1b1,
    const float* __restrict__ r1W2, const float* __restrict__ r1b2,
    const float* __restrict__ r2W1, const float* __restrict__ r2b1,
    const float* __restrict__ r2W2, const float* __restrict__ r2b2,
    const float* __restrict__ Wo,   const float* __restrict__ bo)
{
    __shared__ float CT[128][18];
    __shared__ float A0[128][18];
    __shared__ float A1[128][18];
    __shared__ float ZT[64][18];
    __shared__ float ZEv[64][18];
    __shared__ float KT[64][18];
    __shared__ float AC[64][18];

    const int tid = threadIdx.x;
    const int sb  = blockIdx.x * 16;
    const int jg = tid & 63, sg = tid >> 6;       // sg in 0..7
    const int j2 = jg * 2, s2 = sg * 2;           // 2 neurons x 2 samples
    const int l2 = (tid & 31) * 2, sw = tid >> 5; // Wo stage: 2 outs x 1 sample (sw 0..15)

    for (int idx = tid; idx < 128 * 16; idx += 512) {
        int s = idx >> 7, jj = idx & 127;
        CT[jj][s] = cbuf[(size_t)(sb + s) * 128 + jj];
    }
    for (int idx = tid; idx < 64 * 16; idx += 512) {
        int s = idx >> 6, jj = idx & 63;
        float z = zs[(size_t)(sb + s) * 64 + jj];
        ZT[jj][s] = z; ZEv[jj][s] = z;
    }
    __syncthreads();

    #pragma unroll 1
    for (int st = 0; st < T_ - 1; ++st) {
        float t0 = times[st], t1 = times[st + 1];
        float dt = t1 - t0;
        float tm = t0 + 0.5f * dt;

        #pragma unroll 1
        for (int e = 0; e < 4; ++e) {
            float t = (e == 0) ? t0 : ((e == 3) ? t1 : tm);

            // ---- stage 1: A0 = tanh(c + t*Wi_t + z @ Wi_z) ----
            {
                float2 wt = *(const float2*)(Wi + 64 * 128 + j2);
                float2 ca = *(const float2*)&CT[j2][s2];
                float2 cb = *(const float2*)&CT[j2 + 1][s2];
                float a00 = ca.x + t * wt.x, a01 = ca.y + t * wt.x;
                float a10 = cb.x + t * wt.y, a11 = cb.y + t * wt.y;
                #pragma unroll 8
                for (int k = 0; k < 64; ++k) {
                    float2 w = *(const float2*)(Wi + k * 128 + j2);
                    float2 x = *(const float2*)(&ZEv[k][s2]);
                    a00 += w.x * x.x; a01 += w.x * x.y;
                    a10 += w.y * x.x; a11 += w.y * x.y;
                }
                A0[j2][s2] = tanh_f(a00);     A0[j2][s2 + 1] = tanh_f(a01);
                A0[j2 + 1][s2] = tanh_f(a10); A0[j2 + 1][s2 + 1] = tanh_f(a11);
            }
            __syncthreads();

            // ---- rb1a: A1 = tanh(A0 @ r1W1 + r1b1) ----
            {
                float2 bb = *(const float2*)(r1b1 + j2);
                float a00 = bb.x, a01 = bb.x, a10 = bb.y, a11 = bb.y;
                #pragma unroll 8
                for (int k = 0; k < 128; ++k) {
                    float2 w = *(const float2*)(r1W1 + k * 128 + j2);
                    float2 x = *(const float2*)(&A0[k][s2]);
                    a00 += w.x * x.x; a01 += w.x * x.y;
                    a10 += w.y * x.x; a11 += w.y * x.y;
                }
                A1[j2][s2] = tanh_f(a00);     A1[j2][s2 + 1] = tanh_f(a01);
                A1[j2 + 1][s2] = tanh_f(a10); A1[j2 + 1][s2 + 1] = tanh_f(a11);
            }
            __syncthreads();

            // ---- rb1b: A0 = tanh(A0 + A1 @ r1W2 + r1b2)  (in place: own elem only)
            {
                float2 bb = *(const float2*)(r1b2 + j2);
                float2 ra = *(const float2*)&A0[j2][s2];
                float2 rb = *(const float2*)&A0[j2 + 1][s2];
                float a00 = bb.x + ra.x, a01 = bb.x + ra.y;
                float a10 = bb.y + rb.x, a11 = bb.y + rb.y;
                #pragma unroll 8
                for (int k = 0; k < 128; ++k) {
                    float2 w = *(const float2*)(r1W2 + k * 128 + j2);
                    float2 x = *(const float2*)(&A1[k][s2]);
                    a00 += w.x * x.x; a01 += w.x * x.y;
                    a10 += w.y * x.x; a11 += w.y * x.y;
                }
                __syncthreads();   // all reads of old A0 done before overwrite? no:
                // NOTE: we only overwrite OUR OWN A0 elements below, and every thread
                // reading A0[k][s2] for this stage read it above (residual ra/rb) or in
                // the k-loop of rb1a which is already past its barrier. The k-loop of
                // THIS stage reads A1, not A0, so in-place update is safe; the barrier
                // above is still required because other threads' residual reads of
                // A0[j2][s2] use only their own elements — strictly private. It is kept
                // for timing symmetry and costs one extra sync per eval.
                A0[j2][s2] = tanh_f(a00);     A0[j2][s2 + 1] = tanh_f(a01);
                A0[j2 + 1][s2] = tanh_f(a10); A0[j2 + 1][s2 + 1] = tanh_f(a11);
            }
            __syncthreads();

            // ---- rb2a ----
            {
                float2 bb = *(const float2*)(r2b1 + j2);
                float a00 = bb.x, a01 = bb.x, a10 = bb.y, a11 = bb.y;
                #pragma unroll 8
                for (int k = 0; k < 128; ++k) {
                    float2 w = *(const float2*)(r2W1 + k * 128 + j2);
                    float2 x = *(const float2*)(&A0[k][s2]);
                    a00 += w.x * x.x; a01 += w.x * x.y;
                    a10 += w.y * x.x; a11 += w.y * x.y;
                }
                A1[j2][s2] = tanh_f(a00);     A1[j2][s2 + 1] = tanh_f(a01);
                A1[j2 + 1][s2] = tanh_f(a10); A1[j2 + 1][s2 + 1] = tanh_f(a11);
            }
            __syncthreads();

            // ---- rb2b ----
            {
                float2 bb = *(const float2*)(r2b2 + j2);
                float2 ra = *(const float2*)&A0[j2][s2];
                float2 rb = *(const float2*)&A0[j2 + 1][s2];
                float a00 = bb.x + ra.x, a01 = bb.x + ra.y;
                float a10 = bb.y + rb.x, a11 = bb.y + rb.y;
                #pragma unroll 8
                for (int k = 0; k < 128; ++k) {
                    float2 w = *(const float2*)(r2W2 + k * 128 + j2);
                    float2 x = *(const float2*)(&A1[k][s2]);
                    a00 += w.x * x.x; a01 += w.x * x.y;
                    a10 += w.y * x.x; a11 += w.y * x.y;
                }
                A0[j2][s2] = tanh_f(a00);     A0[j2][s2 + 1] = tanh_f(a01);
                A0[j2 + 1][s2] = tanh_f(a10); A0[j2 + 1][s2 + 1] = tanh_f(a11);
            }
            __syncthreads();

            // ---- output: KT = A0 @ Wo + bo ----
            {
                float2 bb = *(const float2*)(bo + l2);
                float acc0 = bb.x, acc1 = bb.y;
                #pragma unroll 8
                for (int k = 0; k < 128; ++k) {
                    float2 w = *(const float2*)(Wo + k * 64 + l2);
                    float x = A0[k][sw];
                    acc0 += w.x * x; acc1 += w.y * x;
                }
                KT[l2][sw] = acc0; KT[l2 + 1][sw] = acc1;
            }
            __syncthreads();

            // ---- RK4 glue ----
            for (int idx = tid; idx < 64 * 16; idx += 512) {
                int s = idx >> 6, jj = idx & 63;
                float kv = KT[jj][s];
                if (e == 0) {
                    AC[jj][s] = kv;
                    ZEv[jj][s] = ZT[jj][s] + 0.5f * dt * kv;
                } else if (e == 1) {
                    AC[jj][s] += 2.0f * kv;
                    ZEv[jj][s] = ZT[jj][s] + 0.5f * dt * kv;
                } else if (e == 2) {
                    AC[jj][s] += 2.0f * kv;
                    ZEv[jj][s] = ZT[jj][s] + dt * kv;
                } else {
                    float zn = ZT[jj][s] + (dt * (1.0f / 6.0f)) * (AC[jj][s] + kv);
                    ZT[jj][s] = zn; ZEv[jj][s] = zn;
                    zs[((size_t)(st + 1) * B_ + (sb + s)) * 64 + jj] = zn;
                }
            }
            __syncthreads();
        }
    }
}

// ---------------------------------------------------------------------------
// Kernel 3: decoder  logits[b][t][z] = pred_z @ dec_W + dec_b
// Block = 32 rows x 128 cols; thread = 4 rows x 4 cols, K=64.
// ---------------------------------------------------------------------------
__global__ __launch_bounds__(256) void dec_kernel(
    const float* __restrict__ zsAll,  // [T][B][64]
    const float* __restrict__ dW,     // [64][1000]
    const float* __restrict__ db,     // [1000]
    float* __restrict__ outL)         // [B][T][1000]
{
    __shared__ float At[64][36];      // [k][row], pad 36 for aligned float4 + bank spread

    const int tid = threadIdx.x;
    const int bid = blockIdx.x;
    const int rowblk = bid >> 3, colblk = bid & 7;
    const int rowbase = rowblk * 32;
    const int colbase = colblk * 128;

    for (int idx = tid; idx < 32 * 64; idx += 256) {
        int r = idx >> 6, l = idx & 63;
        int row = rowbase + r;              // row = b*T + t
        int b = row / T_, t = row - b * T_;
        At[l][r] = zsAll[((size_t)t * B_ + b) * 64 + l];
    }
    __syncthreads();

    const int r0 = (tid & 7) * 4;
    const int c0 = colbase + (tid >> 3) * 4;
    if (c0 < Z_) {                          // c0 % 4 == 0 and Z_ % 4 == 0 -> whole float4 valid
        float4 bias = *(const float4*)(db + c0);
        float4 acc0 = bias, acc1 = bias, acc2 = bias, acc3 = bias;
        #pragma unroll 8
        for (int k = 0; k < 64; ++k) {
            float4 w = *(const float4*)(dW + k * Z_ + c0);
            float4 a = *(const float4*)&At[k][r0];
            acc0.x += a.x * w.x; acc0.y += a.x * w.y; acc0.z += a.x * w.z; acc0.w += a.x * w.w;
            acc1.x += a.y * w.x; acc1.y += a.y * w.y; acc1.z += a.y * w.z; acc1.w += a.y * w.w;
            acc2.x += a.z * w.x; acc2.y += a.z * w.y; acc2.z += a.z * w.z; acc2.w += a.z * w.w;
            acc3.x += a.w * w.x; acc3.y += a.w * w.y; acc3.z += a.w * w.z; acc3.w += a.w * w.w;
        }
        size_t base = (size_t)(rowbase + r0) * Z_ + c0;
        *(float4*)(outL + base)          = acc0;
        *(float4*)(outL + base + Z_)     = acc1;
        *(float4*)(outL + base + 2 * Z_) = acc2;
        *(float4*)(outL + base + 3 * Z_) = acc3;
    }
}

// ---------------------------------------------------------------------------
extern "C" void kernel_launch(void* const* d_in, const int* in_sizes, int n_in,
                              void* d_out, int out_size, void* d_ws, size_t ws_size,
                              hipStream_t stream)
{
    const float* person  = (const float*)d_in[0];
    const int*   homeid  = (const int*)  d_in[1];
    const int*   workid  = (const int*)  d_in[2];
    const float* purpose = (const float*)d_in[3];
    const float* times   = (const float*)d_in[4];
    const float* eps     = (const float*)d_in[5];
    const float* ztab    = (const float*)d_in[6];
    const float* eW1 = (const float*)d_in[7];
    const float* eb1 = (const float*)d_in[8];
    const float* eW2 = (const float*)d_in[9];
    const float* eb2 = (const float*)d_in[10];
    const float* dW  = (const float*)d_in[11];
    const float* db  = (const float*)d_in[12];
    const float* oWi = (const float*)d_in[13];
    const float* obi = (const float*)d_in[14];
    const float* r1W1 = (const float*)d_in[15];
    const float* r1b1 = (const float*)d_in[16];
    const float* r1W2 = (const float*)d_in[17];
    const float* r1b2 = (const float*)d_in[18];
    const float* r2W1 = (const float*)d_in[19];
    const float* r2b1 = (const float*)d_in[20];
    const float* r2W2 = (const float*)d_in[21];
    const float* r2b2 = (const float*)d_in[22];
    const float* oWo = (const float*)d_in[23];
    const float* obo = (const float*)d_in[24];

    float* outLogits = (float*)d_out;                        // [B][T][Z]
    float* outMu = outLogits + (size_t)B_ * T_ * Z_;         // [B][L]
    float* outLv = outMu + (size_t)B_ * L_;                  // [B][L]

    // workspace: zs [T][B][L] (50.3 MB) then cbuf [B][OH] (2 MB)
    float* zs   = (float*)d_ws;
    float* cbuf = zs + (size_t)T_ * B_ * L_;

    hipLaunchKernelGGL(enc_kernel, dim3(B_ / 8), dim3(256), 0, stream,
                       person, homeid, workid, purpose, eps, ztab,
                       eW1, eb1, eW2, eb2, oWi, obi, outMu, outLv, zs, cbuf);

    hipLaunchKernelGGL(ode_kernel, dim3(B_ / 16), dim3(512), 0, stream,
                       zs, cbuf, times, oWi,
                       r1W1, r1b1, r1W2, r1b2, r2W1, r2b1, r2W2, r2b2, oWo, obo);

    hipLaunchKernelGGL(dec_kernel, dim3((B_ * T_ / 32) * 8), dim3(256), 0, stream,
                       zs, dW, db, outLogits);
}